// Round 14
// baseline (156.390 us; speedup 1.0000x reference)
//
#include <hip/hip_runtime.h>
#include <stdint.h>

typedef unsigned short u16;
typedef __bf16 bf16_t;
typedef bf16_t bf16x8 __attribute__((ext_vector_type(8)));
typedef float f32x4 __attribute__((ext_vector_type(4)));

static constexpr int P = 65536;  // H*W; D = C = 256

__device__ __forceinline__ float bfbits2f(uint32_t b) {
    union { uint32_t i; float f; } u; u.i = b << 16; return u.f;
}
__device__ __forceinline__ u16 f2bf(float f) {
    union { float f; uint32_t i; } u; u.f = f;
    uint32_t x = u.i + 0x7FFFu + ((u.i >> 16) & 1u);   // RNE
    return (u16)(x >> 16);
}
__device__ __forceinline__ uint32_t pack2(float a, float b) {
    return (uint32_t)f2bf(a) | ((uint32_t)f2bf(b) << 16);
}

// Runtime input-dtype sniff (insurance; verdict on this harness: f32).
__device__ __forceinline__ int detect_bf16_input(const void* Xg) {
    const uint32_t* Xu = (const uint32_t*)Xg;
    const int lane = (int)(threadIdx.x & 63);
    const uint32_t v = Xu[(size_t)lane * 131071u];
    const uint32_t e = (v >> 7) & 0xFFu;
    unsigned long long m = __ballot(e >= 96u && e <= 135u);
    return __popcll(m) >= 40;
}

// Kernel 1: rs[c] = scale[c]*5/max(||w_c||,1e-8)  AND  W -> bf16 row image.
__global__ __launch_bounds__(64) void coshead_prep(
    const void* __restrict__ Xg, const void* __restrict__ Wg,
    const void* __restrict__ Sg, float* __restrict__ rs_ws,
    u16* __restrict__ wbf)
{
    const int c    = (int)blockIdx.x;
    const int lane = (int)threadIdx.x;
    const int bf   = detect_bf16_input(Xg);
    float s;
    uint2 packed;
    if (bf) {
        const uint2 v = *(const uint2*)((const u16*)Wg + (size_t)c * 256 + lane * 4);
        const float a = bfbits2f(v.x & 0xFFFFu), b = bfbits2f(v.x >> 16);
        const float d = bfbits2f(v.y & 0xFFFFu), e = bfbits2f(v.y >> 16);
        s = a * a + b * b + d * d + e * e;
        packed = v;
    } else {
        const f32x4 v = *(const f32x4*)((const float*)Wg + (size_t)c * 256 + lane * 4);
        s = v[0] * v[0] + v[1] * v[1] + v[2] * v[2] + v[3] * v[3];
        packed.x = pack2(v[0], v[1]);
        packed.y = pack2(v[2], v[3]);
    }
    *(uint2*)(wbf + (size_t)c * 256 + lane * 4) = packed;
    s += __shfl_xor(s, 1);  s += __shfl_xor(s, 2);  s += __shfl_xor(s, 4);
    s += __shfl_xor(s, 8);  s += __shfl_xor(s, 16); s += __shfl_xor(s, 32);
    if (lane == 0) {
        const float sc = bf ? bfbits2f((uint32_t)((const u16*)Sg)[c])
                            : ((const float*)Sg)[c];
        rs_ws[c] = sc * 5.0f / fmaxf(sqrtf(s), 1e-8f);
    }
}

// Kernel 2: out[c,p] = (W@X)[c,p] * rs[c] / max(||x_p||,1e-8), f32 out.
// R13 vm-drain-free schedule + two compounding changes:
//   - A PERMANENTLY IN REGISTERS: af[4][2][4] bf16x8 = 128 VGPRs/thread,
//     loaded once from the L2-resident bf16 W image (static indices only).
//     Deletes the W-DMA and ALL af ds_reads (half the steady LDS reads).
//   - 2 blocks/CU: LDS drops to ~25 KB (just sB dbuf + xs + xinv), block
//     covers 256 classes x 128 pixels, grid 512 => 2 resident blocks/CU,
//     2 waves/SIMD, cross-block pack<->MFMA overlap (R13 had 1 wave/SIMD,
//     83% latency gaps). __launch_bounds__(256,2): 256-reg class fits the
//     ~245-reg live set (spill tripwire: WRITE_SIZE > 80 MB).
//   - steady state: raw s_barrier + lgkmcnt(0) only — NEVER vmcnt(0); the
//     1-deep X carry drains at its consumption next iteration (R13-proven).
// Pack/ssq/reduce/MFMA orders identical to R8/R13 => absmax unchanged.
__global__ __launch_bounds__(256, 2) void coshead_gemm(
    const void* __restrict__ Xg_, const u16* __restrict__ Wbf,
    const float* __restrict__ rs_ws, float* __restrict__ Og)
{
    __shared__ char smem_[16384 + 8192 + 256];
    char*  sB   = smem_;                      // [2][64 pix][8 slots x 16 B] dbuf
    float* xs   = (float*)(smem_ + 16384);    // [32][64] partial ssq
    float* xinv = (float*)(smem_ + 16384 + 8192);  // [64]

    const int t  = (int)threadIdx.x;
    const int l  = t & 63;
    const int w  = t >> 6;
    const int pbase = (int)blockIdx.x * 128;
    const int bf = detect_bf16_input(Xg_);

    const int g    = t & 7;      // pixel octet
    const int r    = t >> 3;     // k-pair row 0..31
    const int m16  = l & 15;
    const int quad = l >> 4;

    // ---- prologue: wave w's 64 classes of A -> registers (R2/R10-proven
    // mapping; all indices compile-time => register-resident) ----
    bf16x8 af[4][2][4];          // [kc][kk][tm] : 128 VGPRs
    {
        const u16* wrow = Wbf + (size_t)(w * 64 + m16) * 256 + quad * 8;
#pragma unroll
        for (int kc = 0; kc < 4; ++kc)
#pragma unroll
            for (int kk = 0; kk < 2; ++kk)
#pragma unroll
                for (int tm = 0; tm < 4; ++tm)
                    af[kc][kk][tm] = *(const bf16x8*)(wrow + kc * 64 + kk * 32 + tm * 16 * 256);
    }

    // ---- X prefetch for iteration 0 (issued after A loads) ----
    f32x4 rA, rB, rC, rD;          // f32 carry
    uint4 vb0, vb1;                // bf16 carry
    if (bf) {
        const u16* xp = (const u16*)Xg_ + (size_t)(2 * r) * P + pbase + g * 8;
        vb0 = *(const uint4*)xp;
        vb1 = *(const uint4*)(xp + P);
    } else {
        const float* xp = (const float*)Xg_ + (size_t)(2 * r) * P + pbase + g * 8;
        rA = *(const f32x4*)xp;
        rB = *(const f32x4*)(xp + 4);
        rC = *(const f32x4*)(xp + P);
        rD = *(const f32x4*)(xp + P + 4);
    }

    for (int pt = 0; pt < 2; ++pt) {
        const int p0 = pbase + pt * 64;

        float ssq[8];
#pragma unroll
        for (int j = 0; j < 8; ++j) ssq[j] = 0.f;
        f32x4 acc[4][4];
#pragma unroll
        for (int a = 0; a < 4; ++a)
#pragma unroll
            for (int b = 0; b < 4; ++b)
#pragma unroll
                for (int i = 0; i < 4; ++i) acc[a][b][i] = 0.f;

        for (int kc = 0; kc < 4; ++kc) {
            char* sBw = sB + (kc & 1) * 8192;

            // ---- pack carried X regs -> sBw (fused ssq), R8 formulas ----
            if (bf) {
                const uint32_t e0[4] = {vb0.x, vb0.y, vb0.z, vb0.w};
                const uint32_t e1[4] = {vb1.x, vb1.y, vb1.z, vb1.w};
#pragma unroll
                for (int d = 0; d < 4; ++d) {
                    const float f00 = bfbits2f(e0[d] & 0xFFFFu), f01 = bfbits2f(e0[d] >> 16);
                    const float f10 = bfbits2f(e1[d] & 0xFFFFu), f11 = bfbits2f(e1[d] >> 16);
                    ssq[2 * d]     += f00 * f00 + f10 * f10;
                    ssq[2 * d + 1] += f01 * f01 + f11 * f11;
                    const uint32_t d0 = (e0[d] & 0xFFFFu) | (e1[d] << 16);
                    const uint32_t d1 = (e0[d] >> 16) | (e1[d] & 0xFFFF0000u);
                    const int pj0 = g * 8 + 2 * d, pj1 = pj0 + 1;
                    *(uint32_t*)(sBw + pj0 * 128 + (((r >> 2) ^ (pj0 & 7) ^ g) * 16) + (r & 3) * 4) = d0;
                    *(uint32_t*)(sBw + pj1 * 128 + (((r >> 2) ^ (pj1 & 7) ^ g) * 16) + (r & 3) * 4) = d1;
                }
            } else {
                const float f0[8] = {rA[0], rA[1], rA[2], rA[3], rB[0], rB[1], rB[2], rB[3]};
                const float f1[8] = {rC[0], rC[1], rC[2], rC[3], rD[0], rD[1], rD[2], rD[3]};
#pragma unroll
                for (int j = 0; j < 8; ++j) {
                    ssq[j] += f0[j] * f0[j] + f1[j] * f1[j];
                    const int pix = g * 8 + j;
                    *(uint32_t*)(sBw + pix * 128 + (((r >> 2) ^ (pix & 7) ^ g) * 16) + (r & 3) * 4) =
                        pack2(f0[j], f1[j]);
                }
            }

            // ---- issue next iteration's X loads (survive barriers+MFMA) ----
            const int it = pt * 4 + kc;
            if (it < 7) {
                const int nk = (it + 1) & 3, np = (it + 1) >> 2;
                if (bf) {
                    const u16* xp = (const u16*)Xg_ + (size_t)(2 * r + nk * 64) * P
                                    + pbase + np * 64 + g * 8;
                    vb0 = *(const uint4*)xp;
                    vb1 = *(const uint4*)(xp + P);
                } else {
                    const float* xp = (const float*)Xg_ + (size_t)(2 * r + nk * 64) * P
                                      + pbase + np * 64 + g * 8;
                    rA = *(const f32x4*)xp;
                    rB = *(const f32x4*)(xp + 4);
                    rC = *(const f32x4*)(xp + P);
                    rD = *(const f32x4*)(xp + P + 4);
                }
            }

            // ---- raw barrier: LDS visibility only, NO vm drain ----
            asm volatile("s_waitcnt lgkmcnt(0)" ::: "memory");
            __builtin_amdgcn_sched_barrier(0);
            __builtin_amdgcn_s_barrier();

            // ---- MFMA: A from registers, B via 8 ds_read_b128 ----
#pragma unroll
            for (int kk = 0; kk < 2; ++kk) {
                bf16x8 bfr[4];
#pragma unroll
                for (int tn = 0; tn < 4; ++tn) {
                    const int pix = tn * 16 + m16;
                    bfr[tn] = *(const bf16x8*)(sBw + pix * 128 +
                               (((kk * 4 + quad) ^ (pix & 7) ^ (pix >> 3)) * 16));
                }
#pragma unroll
                for (int tm = 0; tm < 4; ++tm)
#pragma unroll
                    for (int tn = 0; tn < 4; ++tn)
                        acc[tm][tn] = __builtin_amdgcn_mfma_f32_16x16x32_bf16(
                            af[kc][kk][tm], bfr[tn], acc[tm][tn], 0, 0, 0);
            }
            // no trailing barrier: next pack writes the OTHER sB buffer; any
            // same-buffer rewrite is 2 barriers away in program order.
        }

        // ---- ptile epilogue (raw barriers; X[pt+1,0] stays in flight) ----
        asm volatile("s_waitcnt lgkmcnt(0)" ::: "memory");
        __builtin_amdgcn_sched_barrier(0);
        __builtin_amdgcn_s_barrier();          // all waves done MFMA[pt,3]
#pragma unroll
        for (int j = 0; j < 8; ++j) xs[r * 64 + g * 8 + j] = ssq[j];
        asm volatile("s_waitcnt lgkmcnt(0)" ::: "memory");
        __builtin_amdgcn_sched_barrier(0);
        __builtin_amdgcn_s_barrier();          // xs visible
        if (t < 64) {
            float sx = 0.f;
#pragma unroll
            for (int rr = 0; rr < 32; ++rr) sx += xs[rr * 64 + t];
            xinv[t] = 1.0f / fmaxf(sqrtf(sx), 1e-8f);
        }
        asm volatile("s_waitcnt lgkmcnt(0)" ::: "memory");
        __builtin_amdgcn_sched_barrier(0);
        __builtin_amdgcn_s_barrier();          // xinv visible

        // ---- scaled f32 store. class = w*64+tm*16+quad*4+i ; pixel = p0+tn*16+m16 ----
        float inv4[4];
#pragma unroll
        for (int tn = 0; tn < 4; ++tn) inv4[tn] = xinv[tn * 16 + m16];
#pragma unroll
        for (int tm = 0; tm < 4; ++tm) {
            const int cbase = w * 64 + tm * 16 + quad * 4;
            const f32x4 rs4 = *(const f32x4*)(rs_ws + cbase);
#pragma unroll
            for (int tn = 0; tn < 4; ++tn) {
#pragma unroll
                for (int i = 0; i < 4; ++i) {
                    Og[(size_t)(cbase + i) * P + p0 + tn * 16 + m16] =
                        acc[tm][tn][i] * rs4[i] * inv4[tn];
                }
            }
        }
        // no barrier here: next ptile's first pack writes sB buffer0 (last
        // read before the previous kc-loop's barriers); xinv rewrite is 3
        // barriers away.
    }
}

extern "C" void kernel_launch(void* const* d_in, const int* in_sizes, int n_in,
                              void* d_out, int out_size, void* d_ws, size_t ws_size,
                              hipStream_t stream) {
    (void)out_size; (void)ws_size;
    const void* X = d_in[0];
    const void* W = d_in[1];
    const void* S = d_in[2];
    for (int i = 0; i < n_in; ++i) {
        if (in_sizes[i] == 256 * 65536) X = d_in[i];
        else if (in_sizes[i] == 256 * 256) W = d_in[i];
        else if (in_sizes[i] == 256)      S = d_in[i];
    }
    float* rs  = (float*)d_ws;
    u16*   wbf = (u16*)((char*)d_ws + 1024);   // 128 KB bf16 W image
    coshead_prep<<<dim3(256), dim3(64), 0, stream>>>(X, W, S, rs, wbf);
    coshead_gemm<<<dim3(512), dim3(256), 0, stream>>>(X, wbf, rs, (float*)d_out);
}

// Round 15
// 127.091 us; speedup vs baseline: 1.2305x; 1.2305x over previous
//
#include <hip/hip_runtime.h>
#include <stdint.h>

typedef unsigned short u16;
typedef __bf16 bf16_t;
typedef bf16_t bf16x8 __attribute__((ext_vector_type(8)));
typedef float f32x4 __attribute__((ext_vector_type(4)));

static constexpr int P = 65536;  // H*W; D = C = 256

__device__ __forceinline__ float bfbits2f(uint32_t b) {
    union { uint32_t i; float f; } u; u.i = b << 16; return u.f;
}
__device__ __forceinline__ u16 f2bf(float f) {
    union { float f; uint32_t i; } u; u.f = f;
    uint32_t x = u.i + 0x7FFFu + ((u.i >> 16) & 1u);   // RNE
    return (u16)(x >> 16);
}
__device__ __forceinline__ uint32_t pack2(float a, float b) {
    return (uint32_t)f2bf(a) | ((uint32_t)f2bf(b) << 16);
}

// Runtime input-dtype sniff (insurance; verdict on this harness: f32).
__device__ __forceinline__ int detect_bf16_input(const void* Xg) {
    const uint32_t* Xu = (const uint32_t*)Xg;
    const int lane = (int)(threadIdx.x & 63);
    const uint32_t v = Xu[(size_t)lane * 131071u];
    const uint32_t e = (v >> 7) & 0xFFu;
    unsigned long long m = __ballot(e >= 96u && e <= 135u);
    return __popcll(m) >= 40;
}

// Kernel 1: rs[c] = scale[c]*5/max(||w_c||,1e-8)  AND  W -> bf16 row image.
__global__ __launch_bounds__(64) void coshead_prep(
    const void* __restrict__ Xg, const void* __restrict__ Wg,
    const void* __restrict__ Sg, float* __restrict__ rs_ws,
    u16* __restrict__ wbf)
{
    const int c    = (int)blockIdx.x;
    const int lane = (int)threadIdx.x;
    const int bf   = detect_bf16_input(Xg);
    float s;
    uint2 packed;
    if (bf) {
        const uint2 v = *(const uint2*)((const u16*)Wg + (size_t)c * 256 + lane * 4);
        const float a = bfbits2f(v.x & 0xFFFFu), b = bfbits2f(v.x >> 16);
        const float d = bfbits2f(v.y & 0xFFFFu), e = bfbits2f(v.y >> 16);
        s = a * a + b * b + d * d + e * e;
        packed = v;
    } else {
        const f32x4 v = *(const f32x4*)((const float*)Wg + (size_t)c * 256 + lane * 4);
        s = v[0] * v[0] + v[1] * v[1] + v[2] * v[2] + v[3] * v[3];
        packed.x = pack2(v[0], v[1]);
        packed.y = pack2(v[2], v[3]);
    }
    *(uint2*)(wbf + (size_t)c * 256 + lane * 4) = packed;
    s += __shfl_xor(s, 1);  s += __shfl_xor(s, 2);  s += __shfl_xor(s, 4);
    s += __shfl_xor(s, 8);  s += __shfl_xor(s, 16); s += __shfl_xor(s, 32);
    if (lane == 0) {
        const float sc = bf ? bfbits2f((uint32_t)((const u16*)Sg)[c])
                            : ((const float*)Sg)[c];
        rs_ws[c] = sc * 5.0f / fmaxf(sqrtf(s), 1e-8f);
    }
}

// Kernel 2: out[c,p] = (W@X)[c,p] * rs[c] / max(||x_p||,1e-8), f32 out.
// R13 vm-drain-free schedule (champion, 44us) with two budget-safe changes:
//   - A PERMANENTLY IN REGISTERS af[4][2][4] (R14-proven mapping) at the
//     (256,1) 512-reg budget where spill is IMPOSSIBLE (R14's failure was
//     the (256,2) 256-reg cap). Deletes the 128 KB W-DMA prologue and all
//     af ds_reads (steady LDS reads halve). LDS 148 -> 25 KB.
//   - 2-DEEP X prefetch: two 16-reg carry sets alternated by kc parity
//     (static, rule-20-safe). Each load batch gets ~2 iterations to land ->
//     smooths the bursty 1-deep demand that kept R13 at ~50% of per-CU BW.
//   - steady state unchanged: raw s_barrier + lgkmcnt(0) only, NEVER
//     vmcnt(0); epilogue stores drain lazily (counted waits leave them
//     in flight).
// Pack/ssq/reduce/MFMA/store orders identical to R13 => absmax unchanged.
__global__ __launch_bounds__(256, 1) void coshead_gemm(
    const void* __restrict__ Xg_, const u16* __restrict__ Wbf,
    const float* __restrict__ rs_ws, float* __restrict__ Og)
{
    __shared__ char smem_[16384 + 8192 + 256];
    char*  sB   = smem_;                           // [2][64 pix][8 slots x 16 B] dbuf
    float* xs   = (float*)(smem_ + 16384);         // [32][64] partial ssq
    float* xinv = (float*)(smem_ + 16384 + 8192);  // [64]

    const int t  = (int)threadIdx.x;
    const int l  = t & 63;
    const int w  = t >> 6;
    const int pbase = (int)blockIdx.x * 256;
    const int bf = detect_bf16_input(Xg_);

    const int g    = t & 7;      // pixel octet
    const int r    = t >> 3;     // k-pair row 0..31
    const int m16  = l & 15;
    const int quad = l >> 4;

    // ---- prologue: wave w's 64 classes of A -> registers (R14-proven) ----
    bf16x8 af[4][2][4];          // [kc][kk][tm] : 128 VGPRs, static idx only
    {
        const u16* wrow = Wbf + (size_t)(w * 64 + m16) * 256 + quad * 8;
#pragma unroll
        for (int kc = 0; kc < 4; ++kc)
#pragma unroll
            for (int kk = 0; kk < 2; ++kk)
#pragma unroll
                for (int tm = 0; tm < 4; ++tm)
                    af[kc][kk][tm] = *(const bf16x8*)(wrow + kc * 64 + kk * 32 + tm * 16 * 256);
    }

    // ---- 2-deep X prefetch: set0 = even iterations, set1 = odd ----
    f32x4 rA0, rB0, rC0, rD0, rA1, rB1, rC1, rD1;   // f32 carries
    uint4 wa0, wa1, wb0, wb1;                        // bf16 carries
    if (bf) {
        const u16* x0 = (const u16*)Xg_ + (size_t)(2 * r) * P + pbase + g * 8;          // it=0
        wa0 = *(const uint4*)x0;
        wa1 = *(const uint4*)(x0 + P);
        const u16* x1 = (const u16*)Xg_ + (size_t)(2 * r + 64) * P + pbase + g * 8;     // it=1
        wb0 = *(const uint4*)x1;
        wb1 = *(const uint4*)(x1 + P);
    } else {
        const float* x0 = (const float*)Xg_ + (size_t)(2 * r) * P + pbase + g * 8;      // it=0
        rA0 = *(const f32x4*)x0;
        rB0 = *(const f32x4*)(x0 + 4);
        rC0 = *(const f32x4*)(x0 + P);
        rD0 = *(const f32x4*)(x0 + P + 4);
        const float* x1 = (const float*)Xg_ + (size_t)(2 * r + 64) * P + pbase + g * 8; // it=1
        rA1 = *(const f32x4*)x1;
        rB1 = *(const f32x4*)(x1 + 4);
        rC1 = *(const f32x4*)(x1 + P);
        rD1 = *(const f32x4*)(x1 + P + 4);
    }

    for (int pt = 0; pt < 4; ++pt) {
        const int p0 = pbase + pt * 64;

        float ssq[8];
#pragma unroll
        for (int j = 0; j < 8; ++j) ssq[j] = 0.f;
        f32x4 acc[4][4];
#pragma unroll
        for (int a = 0; a < 4; ++a)
#pragma unroll
            for (int b = 0; b < 4; ++b)
#pragma unroll
                for (int i = 0; i < 4; ++i) acc[a][b][i] = 0.f;

#pragma unroll
        for (int kc = 0; kc < 4; ++kc) {
            char* sBw = sB + (kc & 1) * 8192;
            const int it = pt * 4 + kc;     // set parity == kc & 1 (pt*4 even)

            // ---- pack carried X regs (set kc&1) -> sBw, fused ssq ----
            if (bf) {
                const uint4 v0 = (kc & 1) ? wb0 : wa0;
                const uint4 v1 = (kc & 1) ? wb1 : wa1;
                const uint32_t e0[4] = {v0.x, v0.y, v0.z, v0.w};
                const uint32_t e1[4] = {v1.x, v1.y, v1.z, v1.w};
#pragma unroll
                for (int d = 0; d < 4; ++d) {
                    const float f00 = bfbits2f(e0[d] & 0xFFFFu), f01 = bfbits2f(e0[d] >> 16);
                    const float f10 = bfbits2f(e1[d] & 0xFFFFu), f11 = bfbits2f(e1[d] >> 16);
                    ssq[2 * d]     += f00 * f00 + f10 * f10;
                    ssq[2 * d + 1] += f01 * f01 + f11 * f11;
                    const uint32_t d0 = (e0[d] & 0xFFFFu) | (e1[d] << 16);
                    const uint32_t d1 = (e0[d] >> 16) | (e1[d] & 0xFFFF0000u);
                    const int pj0 = g * 8 + 2 * d, pj1 = pj0 + 1;
                    *(uint32_t*)(sBw + pj0 * 128 + (((r >> 2) ^ (pj0 & 7) ^ g) * 16) + (r & 3) * 4) = d0;
                    *(uint32_t*)(sBw + pj1 * 128 + (((r >> 2) ^ (pj1 & 7) ^ g) * 16) + (r & 3) * 4) = d1;
                }
            } else {
                const f32x4 cA = (kc & 1) ? rA1 : rA0;
                const f32x4 cB = (kc & 1) ? rB1 : rB0;
                const f32x4 cC = (kc & 1) ? rC1 : rC0;
                const f32x4 cD = (kc & 1) ? rD1 : rD0;
                const float f0[8] = {cA[0], cA[1], cA[2], cA[3], cB[0], cB[1], cB[2], cB[3]};
                const float f1[8] = {cC[0], cC[1], cC[2], cC[3], cD[0], cD[1], cD[2], cD[3]};
#pragma unroll
                for (int j = 0; j < 8; ++j) {
                    ssq[j] += f0[j] * f0[j] + f1[j] * f1[j];
                    const int pix = g * 8 + j;
                    *(uint32_t*)(sBw + pix * 128 + (((r >> 2) ^ (pix & 7) ^ g) * 16) + (r & 3) * 4) =
                        pack2(f0[j], f1[j]);
                }
            }

            // ---- refill this set with X[it+2] (2-deep; drains over ~2 iters) ----
            if (it < 14) {
                const int nj = it + 2;
                const int nk = nj & 3, np = nj >> 2;
                if (bf) {
                    const u16* xp = (const u16*)Xg_ + (size_t)(2 * r + nk * 64) * P
                                    + pbase + np * 64 + g * 8;
                    if (kc & 1) { wb0 = *(const uint4*)xp; wb1 = *(const uint4*)(xp + P); }
                    else        { wa0 = *(const uint4*)xp; wa1 = *(const uint4*)(xp + P); }
                } else {
                    const float* xp = (const float*)Xg_ + (size_t)(2 * r + nk * 64) * P
                                      + pbase + np * 64 + g * 8;
                    if (kc & 1) {
                        rA1 = *(const f32x4*)xp;       rB1 = *(const f32x4*)(xp + 4);
                        rC1 = *(const f32x4*)(xp + P); rD1 = *(const f32x4*)(xp + P + 4);
                    } else {
                        rA0 = *(const f32x4*)xp;       rB0 = *(const f32x4*)(xp + 4);
                        rC0 = *(const f32x4*)(xp + P); rD0 = *(const f32x4*)(xp + P + 4);
                    }
                }
            }

            // ---- raw barrier: LDS visibility only, NO vm drain ----
            asm volatile("s_waitcnt lgkmcnt(0)" ::: "memory");
            __builtin_amdgcn_sched_barrier(0);
            __builtin_amdgcn_s_barrier();

            // ---- MFMA: A from registers, B via 8 ds_read_b128 ----
#pragma unroll
            for (int kk = 0; kk < 2; ++kk) {
                bf16x8 bfr[4];
#pragma unroll
                for (int tn = 0; tn < 4; ++tn) {
                    const int pix = tn * 16 + m16;
                    bfr[tn] = *(const bf16x8*)(sBw + pix * 128 +
                               (((kk * 4 + quad) ^ (pix & 7) ^ (pix >> 3)) * 16));
                }
#pragma unroll
                for (int tm = 0; tm < 4; ++tm)
#pragma unroll
                    for (int tn = 0; tn < 4; ++tn)
                        acc[tm][tn] = __builtin_amdgcn_mfma_f32_16x16x32_bf16(
                            af[kc][kk][tm], bfr[tn], acc[tm][tn], 0, 0, 0);
            }
            // no trailing barrier: next pack writes the OTHER sB buffer; any
            // same-buffer rewrite is 2 barriers away in program order.
        }

        // ---- ptile epilogue (raw barriers; prefetched X stays in flight) ----
        asm volatile("s_waitcnt lgkmcnt(0)" ::: "memory");
        __builtin_amdgcn_sched_barrier(0);
        __builtin_amdgcn_s_barrier();          // all waves done MFMA[pt,3]
#pragma unroll
        for (int j = 0; j < 8; ++j) xs[r * 64 + g * 8 + j] = ssq[j];
        asm volatile("s_waitcnt lgkmcnt(0)" ::: "memory");
        __builtin_amdgcn_sched_barrier(0);
        __builtin_amdgcn_s_barrier();          // xs visible
        if (t < 64) {
            float sx = 0.f;
#pragma unroll
            for (int rr = 0; rr < 32; ++rr) sx += xs[rr * 64 + t];
            xinv[t] = 1.0f / fmaxf(sqrtf(sx), 1e-8f);
        }
        asm volatile("s_waitcnt lgkmcnt(0)" ::: "memory");
        __builtin_amdgcn_sched_barrier(0);
        __builtin_amdgcn_s_barrier();          // xinv visible

        // ---- scaled f32 store. class = w*64+tm*16+quad*4+i ; pixel = p0+tn*16+m16 ----
        float inv4[4];
#pragma unroll
        for (int tn = 0; tn < 4; ++tn) inv4[tn] = xinv[tn * 16 + m16];
#pragma unroll
        for (int tm = 0; tm < 4; ++tm) {
            const int cbase = w * 64 + tm * 16 + quad * 4;
            const f32x4 rs4 = *(const f32x4*)(rs_ws + cbase);
#pragma unroll
            for (int tn = 0; tn < 4; ++tn) {
#pragma unroll
                for (int i = 0; i < 4; ++i) {
                    Og[(size_t)(cbase + i) * P + p0 + tn * 16 + m16] =
                        acc[tm][tn][i] * rs4[i] * inv4[tn];
                }
            }
        }
        // no barrier here: next ptile's first pack targets sB buffer0 (last
        // read 2+ barriers ago); xinv rewrite is 3 barriers away.
    }
}

extern "C" void kernel_launch(void* const* d_in, const int* in_sizes, int n_in,
                              void* d_out, int out_size, void* d_ws, size_t ws_size,
                              hipStream_t stream) {
    (void)out_size; (void)ws_size;
    const void* X = d_in[0];
    const void* W = d_in[1];
    const void* S = d_in[2];
    for (int i = 0; i < n_in; ++i) {
        if (in_sizes[i] == 256 * 65536) X = d_in[i];
        else if (in_sizes[i] == 256 * 256) W = d_in[i];
        else if (in_sizes[i] == 256)      S = d_in[i];
    }
    float* rs  = (float*)d_ws;
    u16*   wbf = (u16*)((char*)d_ws + 1024);   // 128 KB bf16 W image
    coshead_prep<<<dim3(256), dim3(64), 0, stream>>>(X, W, S, rs, wbf);
    coshead_gemm<<<dim3(256), dim3(256), 0, stream>>>(X, wbf, rs, (float*)d_out);
}